// Round 5
// baseline (32.688 us; speedup 1.0000x reference)
//
#include <hip/hip_runtime.h>

// EdgeConv2d: B=4, C=64, N=8192, K=16, C_OUT=64
// out[b,o,n] = relu( max_k ( y1[b, i1(b,n,k), o] + y2[b, i0(b,n,k), o] ) + bias[o] )
// y1 = (W[:,:C] - W[:,C:]) @ x[b],  y2 = W[:,C:] @ x[b]
// y (fp16): y[b][n][s], s<64 -> y1[s], s>=64 -> y2[s-64]. Row = 256 B.
// Gather tiles are XCD-owned: XCD x owns batch x>>1 (2 MB slab -> own L2),
// n-half x&1. Blocks claim tiles via per-XCD counter after reading XCC_ID.

#define BB   4
#define CCH  64
#define NN   8192
#define KK   16
#define CNT_STRIDE 32           // ints; 128 B between per-XCD counters

typedef _Float16 h2 __attribute__((ext_vector_type(2)));
typedef _Float16 h4 __attribute__((ext_vector_type(4)));
typedef int      v4i __attribute__((ext_vector_type(4)));
typedef float    v4f __attribute__((ext_vector_type(4)));

// ---------------------------------------------------------------------------
// Kernel 1: y GEMM (fp32 accumulate, fp16 store). Also zeroes gather counters.
// ---------------------------------------------------------------------------
__global__ __launch_bounds__(256) void gemm_kernel(const float* __restrict__ x,
                                                   const float* __restrict__ W,
                                                   _Float16* __restrict__ y,
                                                   int* __restrict__ cnt) {
    __shared__ float wT[64 * 132];
    __shared__ float xs[64 * 64];

    const int t   = threadIdx.x;
    const int blk = blockIdx.x;               // 512 blocks
    if (blk == 0 && t < 8) cnt[t * CNT_STRIDE] = 0;   // visible to gather after kernel boundary

    const int xcd  = blk & 7;
    const int b    = xcd >> 1;
    const int tile = ((blk >> 3) << 1) | (xcd & 1);   // 0..127
    const int n0   = tile * 64;

    {
        const int sbase = t >> 6;
        const int k     = t & 63;
        #pragma unroll
        for (int i = 0; i < 32; ++i) {
            const int s = sbase + (i << 2);
            float v;
            if (s < CCH) v = W[s * 128 + k] - W[s * 128 + 64 + k];
            else         v = W[(s - CCH) * 128 + 64 + k];
            wT[k * 132 + s] = v;
        }
    }
    {
        const float* xb = x + (size_t)b * CCH * NN + n0;
        #pragma unroll
        for (int i = 0; i < 16; ++i) {
            const int e = t + (i << 8);
            const int k = e >> 6, n = e & 63;
            xs[k * 64 + n] = xb[(size_t)k * NN + n];
        }
    }
    __syncthreads();

    const int c_grp = t & 31;
    const int n_grp = t >> 5;

    float acc[4][8];
    #pragma unroll
    for (int i = 0; i < 4; ++i)
        #pragma unroll
        for (int j = 0; j < 8; ++j) acc[i][j] = 0.f;

    #pragma unroll 8
    for (int k = 0; k < 64; ++k) {
        const float4 wv  = *(const float4*)&wT[k * 132 + 4 * c_grp];
        const float4 xv0 = *(const float4*)&xs[k * 64 + 8 * n_grp];
        const float4 xv1 = *(const float4*)&xs[k * 64 + 8 * n_grp + 4];
        const float wa[4] = {wv.x, wv.y, wv.z, wv.w};
        const float xa[8] = {xv0.x, xv0.y, xv0.z, xv0.w, xv1.x, xv1.y, xv1.z, xv1.w};
        #pragma unroll
        for (int i = 0; i < 4; ++i)
            #pragma unroll
            for (int j = 0; j < 8; ++j)
                acc[i][j] += wa[i] * xa[j];
    }

    _Float16* ybp = y + ((size_t)b * NN + n0) * 128 + 4 * c_grp;
    #pragma unroll
    for (int j = 0; j < 8; ++j) {
        h4 v;
        v.x = (_Float16)acc[0][j]; v.y = (_Float16)acc[1][j];
        v.z = (_Float16)acc[2][j]; v.w = (_Float16)acc[3][j];
        *(h4*)&ybp[(size_t)(8 * n_grp + j) * 128] = v;
    }
}

// ---------------------------------------------------------------------------
// Kernel 2: gather + pk_add + pk_max over K, bias + relu, transposed store.
// 4096 blocks claim 2048 tiles (16 nodes each) XCD-locally; surplus exits.
// ---------------------------------------------------------------------------
__global__ __launch_bounds__(256) void gather_kernel(const _Float16* __restrict__ y,
                                                     const int* __restrict__ edge,
                                                     const float* __restrict__ bias,
                                                     float* __restrict__ out,
                                                     int* __restrict__ cnt) {
    __shared__ int   s_tile;
    __shared__ int   eL[16][2][16];   // [nl][src][k] src0=e1(center->y1), src1=e0(->y2)
    __shared__ float so[16][65];

    const int t = threadIdx.x;
    if (t == 0) {
        unsigned xcc;
        asm volatile("s_getreg_b32 %0, hwreg(HW_REG_XCC_ID)" : "=s"(xcc));
        const int x    = (int)(xcc & 7u);
        const int slot = atomicAdd(&cnt[x * CNT_STRIDE], 1);
        s_tile = (slot < 256) ? (x * 256 + slot) : -1;
    }
    __syncthreads();
    const int tile = s_tile;
    if (tile < 0) return;             // block-uniform

    const int b  = tile >> 9;         // owning batch (its 2 MB slab -> this XCD's L2)
    const int n0 = (tile & 511) * 16;

    if (t < 128) {
        const int src = t >> 6;                 // 0 -> e1, 1 -> e0
        const int f   = (t & 63) << 2;
        const int nl  = f >> 4, k0 = f & 15;
        const size_t eb = (size_t)(src == 0 ? BB + b : b) * NN * KK;
        *(v4i*)&eL[nl][src][k0] =
            __builtin_nontemporal_load((const v4i*)&edge[eb + (size_t)(n0 + nl) * KK + k0]);
    }
    __syncthreads();

    const int w    = t >> 6;
    const int lane = t & 63;
    const int half = lane >> 5;       // which k of each pair
    const int cl   = lane & 31;       // channel pair: {2cl, 2cl+1}

    const float2 bv = *(const float2*)&bias[2 * cl];
    const _Float16* yb = y + (size_t)b * NN * 128;

    #pragma unroll 2
    for (int u = 0; u < 4; ++u) {
        const int nl = 4 * w + u;
        h2 s[8];
        #pragma unroll
        for (int kp = 0; kp < 8; ++kp) {
            const int k  = 2 * kp + half;
            const int i1 = eL[nl][0][k];
            const int i0 = eL[nl][1][k];
            const uint a = *(const uint*)&yb[(size_t)i1 * 128 + 2 * cl];       // y1
            const uint c = *(const uint*)&yb[(size_t)i0 * 128 + 64 + 2 * cl];  // y2
            union { uint u32; h2 h; } ua, uc;
            ua.u32 = a; uc.u32 = c;
            s[kp] = ua.h + uc.h;                // v_pk_add_f16
        }
        h2 m = s[0];
        #pragma unroll
        for (int kp = 1; kp < 8; ++kp) m = __builtin_elementwise_max(m, s[kp]);
        union { int i32; h2 h; } um, uo;
        um.h = m;
        uo.i32 = __shfl_xor(um.i32, 32, 64);
        m = __builtin_elementwise_max(m, uo.h);
        if (half == 0) {
            float2 r;
            r.x = fmaxf((float)m.x + bv.x, 0.f);
            r.y = fmaxf((float)m.y + bv.y, 0.f);
            *(float2*)&so[nl][2 * cl] = r;
        }
    }
    __syncthreads();

    {
        const int c = t >> 2;
        const int q = t & 3;
        v4f v;
        v.x = so[4 * q + 0][c];
        v.y = so[4 * q + 1][c];
        v.z = so[4 * q + 2][c];
        v.w = so[4 * q + 3][c];
        __builtin_nontemporal_store(v, (v4f*)(out + ((size_t)b * CCH + c) * NN + n0 + 4 * q));
    }
}

extern "C" void kernel_launch(void* const* d_in, const int* in_sizes, int n_in,
                              void* d_out, int out_size, void* d_ws, size_t ws_size,
                              hipStream_t stream) {
    (void)in_sizes; (void)n_in; (void)out_size; (void)ws_size;
    const float* x    = (const float*)d_in[0];
    const int*   edge = (const int*)d_in[1];
    const float* W    = (const float*)d_in[2];
    const float* bias = (const float*)d_in[3];
    float*       out  = (float*)d_out;
    _Float16*    y    = (_Float16*)d_ws;                     // [B][N][128] fp16 = 8 MB
    int*         cnt  = (int*)((char*)d_ws + (8u << 20));    // 8 counters, 128 B apart

    gemm_kernel<<<dim3(512), dim3(256), 0, stream>>>(x, W, y, cnt);
    gather_kernel<<<dim3(4096), dim3(256), 0, stream>>>(y, edge, bias, out, cnt);
}

// Round 6
// 31.595 us; speedup vs baseline: 1.0346x; 1.0346x over previous
//
#include <hip/hip_runtime.h>

// EdgeConv2d: B=4, C=64, N=8192, K=16, C_OUT=64
// out[b,o,n] = relu( max_k ( y1[b, i1(b,n,k), o] + y2[b, i0(b,n,k), o] ) + bias[o] )
// y1 = (W[:,:C] - W[:,C:]) @ x[b],  y2 = W[:,C:] @ x[b]
// y slab layout (fp16): y1g/y2g[b][g][n][4]  (g = chan-group of 4, c = 4g..4g+3)
// Gather: block = (b, g, node-chunk); stages y1/y2 slices (128 KB) into LDS,
// random reads become ds_read_b64 — dodges the ~7 TB/s global random-gather limit.

#define BB   4
#define CCH  64
#define NN   8192
#define KK   16

typedef _Float16 h4 __attribute__((ext_vector_type(4)));
typedef int      v4i __attribute__((ext_vector_type(4)));

// ---------------------------------------------------------------------------
// Kernel 1: y GEMM (fp32 accumulate). Epilogue transposes through LDS into the
// slab layout y1g/y2g[b][g][n][4] with coalesced 8 B stores.
// ---------------------------------------------------------------------------
__global__ __launch_bounds__(256) void gemm_kernel(const float* __restrict__ x,
                                                   const float* __restrict__ W,
                                                   _Float16* __restrict__ y1g,
                                                   _Float16* __restrict__ y2g) {
    __shared__ __align__(16) float wT[64 * 132];   // [k][s]; reused as sy16 in epilogue
    __shared__ __align__(16) float xs[64 * 64];    // [k][n]

    const int t   = threadIdx.x;
    const int blk = blockIdx.x;               // 512 blocks
    const int xcd  = blk & 7;
    const int b    = xcd >> 1;
    const int tile = ((blk >> 3) << 1) | (xcd & 1);   // 0..127
    const int n0   = tile * 64;

    // wT[k][s]: s<64 -> W1-W2, s>=64 -> W2. Coalesced W-row reads.
    {
        const int sbase = t >> 6;
        const int k     = t & 63;
        #pragma unroll
        for (int i = 0; i < 32; ++i) {
            const int s = sbase + (i << 2);
            float v;
            if (s < CCH) v = W[s * 128 + k] - W[s * 128 + 64 + k];
            else         v = W[(s - CCH) * 128 + 64 + k];
            wT[k * 132 + s] = v;
        }
    }
    // x tile [64 k][64 n], coalesced.
    {
        const float* xb = x + (size_t)b * CCH * NN + n0;
        #pragma unroll
        for (int i = 0; i < 16; ++i) {
            const int e = t + (i << 8);
            const int k = e >> 6, n = e & 63;
            xs[k * 64 + n] = xb[(size_t)k * NN + n];
        }
    }
    __syncthreads();

    const int c_grp = t & 31;   // s-quad = 4*c_grp
    const int n_grp = t >> 5;   // n = 8*n_grp .. +7

    float acc[4][8];
    #pragma unroll
    for (int i = 0; i < 4; ++i)
        #pragma unroll
        for (int j = 0; j < 8; ++j) acc[i][j] = 0.f;

    #pragma unroll 8
    for (int k = 0; k < 64; ++k) {
        const float4 wv  = *(const float4*)&wT[k * 132 + 4 * c_grp];
        const float4 xv0 = *(const float4*)&xs[k * 64 + 8 * n_grp];
        const float4 xv1 = *(const float4*)&xs[k * 64 + 8 * n_grp + 4];
        const float wa[4] = {wv.x, wv.y, wv.z, wv.w};
        const float xa[8] = {xv0.x, xv0.y, xv0.z, xv0.w, xv1.x, xv1.y, xv1.z, xv1.w};
        #pragma unroll
        for (int i = 0; i < 4; ++i)
            #pragma unroll
            for (int j = 0; j < 8; ++j)
                acc[i][j] += wa[i] * xa[j];
    }

    // ---- Epilogue: acc -> LDS fp16 [n][132 s] -> slab stores ----
    __syncthreads();                        // wT/xs reads done; reuse wT region
    _Float16* sy16 = (_Float16*)wT;         // [64 n][132 s] fp16 = 16.9 KB
    #pragma unroll
    for (int j = 0; j < 8; ++j) {
        const int n = 8 * n_grp + j;
        h4 v;
        v.x = (_Float16)acc[0][j]; v.y = (_Float16)acc[1][j];
        v.z = (_Float16)acc[2][j]; v.w = (_Float16)acc[3][j];
        *(h4*)&sy16[n * 132 + 4 * c_grp] = v;   // ds_write_b64
    }
    __syncthreads();
    {
        const int g  = t >> 4;    // 0..15
        const int nl = t & 15;    // 0..15
        #pragma unroll
        for (int it = 0; it < 4; ++it) {
            const int n = nl + 16 * it;
            const h4 a1 = *(const h4*)&sy16[n * 132 + 4 * g];        // y1: s = 4g..
            const h4 a2 = *(const h4*)&sy16[n * 132 + 64 + 4 * g];   // y2: s = 64+4g..
            const size_t off = ((size_t)(b * 16 + g) * NN + n0 + n) * 4;
            *(h4*)&y1g[off] = a1;   // 16 lanes x 8 B contiguous per slab
            *(h4*)&y2g[off] = a2;
        }
    }
}

// ---------------------------------------------------------------------------
// Kernel 2: LDS-staged gather. 256 blocks = b(4) x g(16) x chunk(4).
// Stage y1/y2 [8192][4] fp16 (128 KB) into LDS; thread-per-node random reads
// are ds_read_b64; bias+relu; coalesced dword stores per channel.
// ---------------------------------------------------------------------------
__global__ __launch_bounds__(256, 1) void gather_kernel(const _Float16* __restrict__ y1g,
                                                        const _Float16* __restrict__ y2g,
                                                        const int* __restrict__ edge,
                                                        const float* __restrict__ bias,
                                                        float* __restrict__ out) {
    __shared__ __align__(16) _Float16 sy1[NN * 4];   // 64 KB, row = 8 B
    __shared__ __align__(16) _Float16 sy2[NN * 4];   // 64 KB

    const int t     = threadIdx.x;
    const int blk   = blockIdx.x;      // 256
    const int b     = blk >> 6;
    const int g     = (blk >> 2) & 15;
    const int chunk = blk & 3;

    // Stage the (b,g) slices: sequential 16 B per thread per iter, coalesced.
    {
        const _Float16* y1s = y1g + (size_t)(b * 16 + g) * NN * 4;
        const _Float16* y2s = y2g + (size_t)(b * 16 + g) * NN * 4;
        #pragma unroll
        for (int i = 0; i < 16; ++i) {
            const int e = (i * 256 + t) * 8;
            *(v4i*)&sy1[e] = *(const v4i*)&y1s[e];
            *(v4i*)&sy2[e] = *(const v4i*)&y2s[e];
        }
    }
    __syncthreads();

    const float4 bv = *(const float4*)&bias[4 * g];
    const int* e1p = edge + (size_t)(BB + b) * NN * KK;   // centers  -> y1
    const int* e0p = edge + (size_t)b * NN * KK;          // neighbors-> y2
    const int cbase = chunk * 2048;

#define EDGE_TERM(I1, I0) ({                                   \
        const h4 a_ = *(const h4*)&sy1[(size_t)(unsigned)(I1) * 4]; \
        const h4 c_ = *(const h4*)&sy2[(size_t)(unsigned)(I0) * 4]; \
        a_ + c_; })

    #pragma unroll 2
    for (int it = 0; it < 8; ++it) {
        const int n = cbase + it * 256 + t;   // lane-contiguous nodes
        const v4i* p1 = (const v4i*)&e1p[(size_t)n * KK];
        const v4i* p0 = (const v4i*)&e0p[(size_t)n * KK];
        const v4i A1 = p1[0], B1 = p1[1], C1 = p1[2], D1 = p1[3];
        const v4i A0 = p0[0], B0 = p0[1], C0 = p0[2], D0 = p0[3];

        h4 m = EDGE_TERM(A1.x, A0.x);
        m = __builtin_elementwise_max(m, EDGE_TERM(A1.y, A0.y));
        m = __builtin_elementwise_max(m, EDGE_TERM(A1.z, A0.z));
        m = __builtin_elementwise_max(m, EDGE_TERM(A1.w, A0.w));
        m = __builtin_elementwise_max(m, EDGE_TERM(B1.x, B0.x));
        m = __builtin_elementwise_max(m, EDGE_TERM(B1.y, B0.y));
        m = __builtin_elementwise_max(m, EDGE_TERM(B1.z, B0.z));
        m = __builtin_elementwise_max(m, EDGE_TERM(B1.w, B0.w));
        m = __builtin_elementwise_max(m, EDGE_TERM(C1.x, C0.x));
        m = __builtin_elementwise_max(m, EDGE_TERM(C1.y, C0.y));
        m = __builtin_elementwise_max(m, EDGE_TERM(C1.z, C0.z));
        m = __builtin_elementwise_max(m, EDGE_TERM(C1.w, C0.w));
        m = __builtin_elementwise_max(m, EDGE_TERM(D1.x, D0.x));
        m = __builtin_elementwise_max(m, EDGE_TERM(D1.y, D0.y));
        m = __builtin_elementwise_max(m, EDGE_TERM(D1.z, D0.z));
        m = __builtin_elementwise_max(m, EDGE_TERM(D1.w, D0.w));

        float* ob = out + ((size_t)b * CCH + 4 * g) * NN + n;
        ob[0]          = fmaxf((float)m.x + bv.x, 0.f);
        ob[NN]         = fmaxf((float)m.y + bv.y, 0.f);
        ob[2 * (size_t)NN] = fmaxf((float)m.z + bv.z, 0.f);
        ob[3 * (size_t)NN] = fmaxf((float)m.w + bv.w, 0.f);
    }
#undef EDGE_TERM
}

extern "C" void kernel_launch(void* const* d_in, const int* in_sizes, int n_in,
                              void* d_out, int out_size, void* d_ws, size_t ws_size,
                              hipStream_t stream) {
    (void)in_sizes; (void)n_in; (void)out_size; (void)ws_size;
    const float* x    = (const float*)d_in[0];
    const int*   edge = (const int*)d_in[1];
    const float* W    = (const float*)d_in[2];
    const float* bias = (const float*)d_in[3];
    float*       out  = (float*)d_out;
    _Float16*    y1g  = (_Float16*)d_ws;                       // [B][16][N][4] fp16 = 4 MB
    _Float16*    y2g  = (_Float16*)((char*)d_ws + (4u << 20)); // 4 MB

    gemm_kernel<<<dim3(512), dim3(256), 0, stream>>>(x, W, y1g, y2g);
    gather_kernel<<<dim3(256), dim3(256), 0, stream>>>(y1g, y2g, edge, bias, out);
}